// Round 1
// baseline (877.924 us; speedup 1.0000x reference)
//
#include <hip/hip_runtime.h>

// Problem constants
#define G_GRAPHS 1024
#define N_NODES  40
#define M_EDGES  780          // N*(N-1)/2
#define NUM_NODES (G_GRAPHS * N_NODES)          // 40960
#define H_ELEMS  (NUM_NODES * 64)               // 2621440
#define X_STRIDE (4 * N_NODES)                  // 160
#define X_PER_G  (X_STRIDE * X_STRIDE)          // 25600

#define SLOPE 0.1f

__device__ __forceinline__ float lrelu(float v) {
    return fmaxf(v, SLOPE * v);
}

// ---------------------------------------------------------------------------
// K0: transpose Wn0 and We0 (64x64) into workspace so the MLP L1 dot can
// stream contiguous rows with uniform (scalar) loads.
// ---------------------------------------------------------------------------
__global__ __launch_bounds__(256) void k_prep(const float* __restrict__ Wn0,
                                              const float* __restrict__ We0,
                                              float* __restrict__ W0Tn,
                                              float* __restrict__ W0Te) {
    int t = blockIdx.x * 256 + threadIdx.x;   // 0..8191
    if (t < 4096) {
        int k = t >> 6, m = t & 63;
        W0Tn[k * 64 + m] = Wn0[m * 64 + k];
    } else {
        int t2 = t - 4096;
        int k = t2 >> 6, m = t2 & 63;
        W0Te[k * 64 + m] = We0[m * 64 + k];
    }
}

// ---------------------------------------------------------------------------
// K1: 3-layer GCN, one block per graph. Complete graph minus self-loops with
// deg==39 everywhere => aggregation = (colsum - own)/39 + b.
// Writes h3 (a.k.a. hg) straight into the h-region of d_out.
// ---------------------------------------------------------------------------
__global__ __launch_bounds__(256) void k_gcn(const float* __restrict__ x,
                                             const float* __restrict__ Wg0,
                                             const float* __restrict__ bg0,
                                             const float* __restrict__ Wg1,
                                             const float* __restrict__ bg1,
                                             const float* __restrict__ Wg2,
                                             const float* __restrict__ bg2,
                                             float* __restrict__ hout) {
    __shared__ float h0[N_NODES * 6];
    __shared__ float buf[N_NODES * 64];
    __shared__ float S[64];
    __shared__ float h1[N_NODES * 32];
    __shared__ float h2[N_NODES * 32];

    const int g = blockIdx.x;
    const int tid = threadIdx.x;
    const float inv39 = 1.0f / 39.0f;

    // load x[:, :6] for this graph's 40 nodes
    for (int idx = tid; idx < N_NODES * 6; idx += 256) {
        int n = idx / 6, f = idx - n * 6;
        h0[idx] = x[(g * N_NODES + n) * 16 + f];
    }
    __syncthreads();

    // ---- layer 0: (40x6)@(6x32) ----
    for (int idx = tid; idx < N_NODES * 32; idx += 256) {
        int n = idx >> 5, c = idx & 31;
        float s = 0.f;
#pragma unroll
        for (int f = 0; f < 6; f++) s += h0[n * 6 + f] * Wg0[f * 32 + c];
        buf[n * 32 + c] = s;
    }
    __syncthreads();
    if (tid < 32) {
        float s = 0.f;
        for (int n = 0; n < N_NODES; n++) s += buf[n * 32 + tid];
        S[tid] = s;
    }
    __syncthreads();
    for (int idx = tid; idx < N_NODES * 32; idx += 256) {
        int n = idx >> 5, c = idx & 31;
        float v = (S[c] - buf[n * 32 + c]) * inv39 + bg0[c];
        h1[idx] = lrelu(v);
    }
    __syncthreads();

    // ---- layer 1: (40x32)@(32x32) ----
    for (int idx = tid; idx < N_NODES * 32; idx += 256) {
        int n = idx >> 5, c = idx & 31;
        float s = 0.f;
#pragma unroll
        for (int m = 0; m < 32; m++) s += h1[n * 32 + m] * Wg1[m * 32 + c];
        buf[n * 32 + c] = s;
    }
    __syncthreads();
    if (tid < 32) {
        float s = 0.f;
        for (int n = 0; n < N_NODES; n++) s += buf[n * 32 + tid];
        S[tid] = s;
    }
    __syncthreads();
    for (int idx = tid; idx < N_NODES * 32; idx += 256) {
        int n = idx >> 5, c = idx & 31;
        float v = (S[c] - buf[n * 32 + c]) * inv39 + bg1[c];
        h2[idx] = lrelu(v);
    }
    __syncthreads();

    // ---- layer 2: (40x32)@(32x64), linear ----
    for (int idx = tid; idx < N_NODES * 64; idx += 256) {
        int n = idx >> 6, c = idx & 63;
        float s = 0.f;
#pragma unroll
        for (int m = 0; m < 32; m++) s += h2[n * 32 + m] * Wg2[m * 64 + c];
        buf[idx] = s;
    }
    __syncthreads();
    if (tid < 64) {
        float s = 0.f;
        for (int n = 0; n < N_NODES; n++) s += buf[n * 64 + tid];
        S[tid] = s;
    }
    __syncthreads();
    for (int idx = tid; idx < N_NODES * 64; idx += 256) {
        int n = idx >> 6, c = idx & 63;
        float v = (S[c] - buf[n * 64 + c]) * inv39 + bg2[c];
        hout[(g * N_NODES + n) * 64 + c] = v;
    }
}

// ---------------------------------------------------------------------------
// Shared MLP core: e[64] (regs) -> 64 -> 64 -> 10, weights via uniform loads.
// z1 is never materialized: each z1_k immediately fans out into acc[64].
// ---------------------------------------------------------------------------
__device__ __forceinline__ void mlp_64_64_10(const float e[64],
                                             const float* __restrict__ W0T,
                                             const float* __restrict__ b0,
                                             const float* __restrict__ W1,
                                             const float* __restrict__ b1,
                                             const float* __restrict__ W2,
                                             const float* __restrict__ b2,
                                             float ep[10]) {
    float acc[64];
#pragma unroll
    for (int j = 0; j < 64; j++) acc[j] = b1[j];

#pragma unroll 2
    for (int k = 0; k < 64; k++) {
        const float* w = W0T + k * 64;   // uniform address -> s_load
        float s0 = 0.f, s1 = 0.f, s2 = 0.f, s3 = 0.f;
#pragma unroll
        for (int m = 0; m < 64; m += 4) {
            s0 += e[m + 0] * w[m + 0];
            s1 += e[m + 1] * w[m + 1];
            s2 += e[m + 2] * w[m + 2];
            s3 += e[m + 3] * w[m + 3];
        }
        float z = (s0 + s1) + (s2 + s3) + b0[k];
        z = lrelu(z);
        const float* w1 = W1 + k * 64;   // uniform address -> s_load
#pragma unroll
        for (int j = 0; j < 64; j++) acc[j] += z * w1[j];
    }

#pragma unroll
    for (int t = 0; t < 10; t++) ep[t] = b2[t];
#pragma unroll
    for (int k = 0; k < 64; k++) {
        float z = lrelu(acc[k]);
        const float* w2 = W2 + k * 10;
#pragma unroll
        for (int t = 0; t < 10; t++) ep[t] += z * w2[t];
    }
}

__device__ __forceinline__ void make_block_rows(const float ep[10],
                                                float4& r0, float4& r1,
                                                float4& r2, float4& r3) {
    // SMAT_IDX = [0,1,2,3, 1,4,5,6, 2,5,7,8, 3,6,8,9]
    r0 = make_float4(ep[0], ep[1], ep[2], ep[3]);
    r1 = make_float4(ep[1], ep[4], ep[5], ep[6]);
    r2 = make_float4(ep[2], ep[5], ep[7], ep[8]);
    r3 = make_float4(ep[3], ep[6], ep[8], ep[9]);
}

// ---------------------------------------------------------------------------
// K2: node MLP (vp) -> diagonal 4x4 blocks of X. One thread per node.
// ---------------------------------------------------------------------------
__global__ __launch_bounds__(256) void k_vp(const float* __restrict__ hg,
                                            const float* __restrict__ W0T,
                                            const float* __restrict__ b0,
                                            const float* __restrict__ W1,
                                            const float* __restrict__ b1,
                                            const float* __restrict__ W2,
                                            const float* __restrict__ b2,
                                            float* __restrict__ X) {
    int n = blockIdx.x * 256 + threadIdx.x;   // 0..40959, exact grid
    int g = n / N_NODES;
    int iloc = n - g * N_NODES;

    float e[64];
    const float4* hr = (const float4*)(hg + n * 64);
#pragma unroll
    for (int q = 0; q < 16; q++) {
        float4 v = hr[q];
        e[4 * q + 0] = v.x; e[4 * q + 1] = v.y;
        e[4 * q + 2] = v.z; e[4 * q + 3] = v.w;
    }

    float ep[10];
    mlp_64_64_10(e, W0T, b0, W1, b1, W2, b2, ep);

    float4 r0, r1, r2, r3;
    make_block_rows(ep, r0, r1, r2, r3);
    float* base = X + g * X_PER_G + (4 * iloc) * X_STRIDE + 4 * iloc;
    *(float4*)(base + 0 * X_STRIDE) = r0;
    *(float4*)(base + 1 * X_STRIDE) = r1;
    *(float4*)(base + 2 * X_STRIDE) = r2;
    *(float4*)(base + 3 * X_STRIDE) = r3;
}

// ---------------------------------------------------------------------------
// K3: edge MLP (ep) -> off-diagonal 4x4 blocks (i,j) and (j,i).
// One thread per upper-triangular edge; 1024*780 = 3120*256 exactly.
// ---------------------------------------------------------------------------
__global__ __launch_bounds__(256) void k_edge(const float* __restrict__ hg,
                                              const float* __restrict__ W0T,
                                              const float* __restrict__ b0,
                                              const float* __restrict__ W1,
                                              const float* __restrict__ b1,
                                              const float* __restrict__ W2,
                                              const float* __restrict__ b2,
                                              float* __restrict__ X) {
    int eid = blockIdx.x * 256 + threadIdx.x;   // 0..798719, exact grid
    int g = eid / M_EDGES;
    int m = eid - g * M_EDGES;

    // decode triu(N,1) pair (i,j) from linear index m
    int i = 0, rem = m;
    while (rem >= (N_NODES - 1) - i) { rem -= (N_NODES - 1) - i; ++i; }
    int j = i + 1 + rem;

    const float4* ha = (const float4*)(hg + (g * N_NODES + i) * 64);
    const float4* hb = (const float4*)(hg + (g * N_NODES + j) * 64);
    float e[64];
#pragma unroll
    for (int q = 0; q < 16; q++) {
        float4 a = ha[q], b = hb[q];
        e[4 * q + 0] = a.x + b.x; e[4 * q + 1] = a.y + b.y;
        e[4 * q + 2] = a.z + b.z; e[4 * q + 3] = a.w + b.w;
    }

    float ep[10];
    mlp_64_64_10(e, W0T, b0, W1, b1, W2, b2, ep);

    float4 r0, r1, r2, r3;
    make_block_rows(ep, r0, r1, r2, r3);

    float* Xg = X + g * X_PER_G;
    // block (i,j)
    float* p = Xg + (4 * i) * X_STRIDE + 4 * j;
    *(float4*)(p + 0 * X_STRIDE) = r0;
    *(float4*)(p + 1 * X_STRIDE) = r1;
    *(float4*)(p + 2 * X_STRIDE) = r2;
    *(float4*)(p + 3 * X_STRIDE) = r3;
    // block (j,i): the 4x4 block is symmetric, so same rows
    float* q2 = Xg + (4 * j) * X_STRIDE + 4 * i;
    *(float4*)(q2 + 0 * X_STRIDE) = r0;
    *(float4*)(q2 + 1 * X_STRIDE) = r1;
    *(float4*)(q2 + 2 * X_STRIDE) = r2;
    *(float4*)(q2 + 3 * X_STRIDE) = r3;
}

// ---------------------------------------------------------------------------
// Launch
// ---------------------------------------------------------------------------
extern "C" void kernel_launch(void* const* d_in, const int* in_sizes, int n_in,
                              void* d_out, int out_size, void* d_ws, size_t ws_size,
                              hipStream_t stream) {
    const float* x   = (const float*)d_in[0];
    // d_in[1] edge_index, d_in[2] ud_edges, d_in[3] edge_map: structure is
    // deterministic (complete graph, triu ordering) -> derived analytically.
    const float* Wg0 = (const float*)d_in[4];
    const float* bg0 = (const float*)d_in[5];
    const float* Wg1 = (const float*)d_in[6];
    const float* bg1 = (const float*)d_in[7];
    const float* Wg2 = (const float*)d_in[8];
    const float* bg2 = (const float*)d_in[9];
    const float* Wn0 = (const float*)d_in[10];
    const float* bn0 = (const float*)d_in[11];
    const float* Wn1 = (const float*)d_in[12];
    const float* bn1 = (const float*)d_in[13];
    const float* Wn2 = (const float*)d_in[14];
    const float* bn2 = (const float*)d_in[15];
    const float* We0 = (const float*)d_in[16];
    const float* be0 = (const float*)d_in[17];
    const float* We1 = (const float*)d_in[18];
    const float* be1 = (const float*)d_in[19];
    const float* We2 = (const float*)d_in[20];
    const float* be2 = (const float*)d_in[21];

    float* hout = (float*)d_out;            // h: 40960 x 64
    float* X    = hout + H_ELEMS;           // X: 1024 x 160 x 160

    float* W0Tn = (float*)d_ws;             // 4096 floats
    float* W0Te = W0Tn + 4096;              // 4096 floats

    k_prep<<<32, 256, 0, stream>>>(Wn0, We0, W0Tn, W0Te);
    k_gcn<<<G_GRAPHS, 256, 0, stream>>>(x, Wg0, bg0, Wg1, bg1, Wg2, bg2, hout);
    k_vp<<<NUM_NODES / 256, 256, 0, stream>>>(hout, W0Tn, bn0, Wn1, bn1, Wn2, bn2, X);
    k_edge<<<(G_GRAPHS * M_EDGES) / 256, 256, 0, stream>>>(hout, W0Te, be0, We1, be1, We2, be2, X);
}